// Round 1
// baseline (270.216 us; speedup 1.0000x reference)
//
#include <hip/hip_runtime.h>
#include <math.h>

#define BB 8
#define CC 512
#define LL 4096
#define GG 4
#define GS 128
#define KK 3
#define EPSV 1e-5f

#define TL 8            // l-positions per tile in fused kernel
#define XS_STRIDE 11    // TL+2 = 10 used, stride 11 (gcd(11,32)=1 -> conflict-free)
#define FT_STRIDE 516   // C + 4 pad

// ws layout (floats):
//  [0,      4096) : psum[c*8+b]
//  [4096,   8192) : psq [c*8+b]
//  [8192,   8704) : scale[c]
//  [8704,   9216) : shift[c]   (= beta - mean*scale)

// ---------------- K1: conv + per-(c,b) partial stats ----------------
__global__ __launch_bounds__(256) void conv_stats_kernel(
    const float* __restrict__ x, const float* __restrict__ conv_w,
    const float* __restrict__ conv_b, float* __restrict__ ws)
{
    const int c = blockIdx.x;
    const int b = blockIdx.y;
    const int t = threadIdx.x;

    const float w0 = conv_w[c * 3 + 0];
    const float w1 = conv_w[c * 3 + 1];
    const float w2 = conv_w[c * 3 + 2];
    const float cb = conv_b[c];
    const float* xr = x + ((size_t)b * CC + c) * LL;

    const int l0 = t * 16;   // 256 threads * 16 = 4096
    float v[18];
    v[0] = (l0 == 0) ? 0.f : xr[l0 - 1];
#pragma unroll
    for (int i = 0; i < 4; ++i) {
        float4 q = *reinterpret_cast<const float4*>(xr + l0 + i * 4);
        v[1 + i * 4 + 0] = q.x; v[1 + i * 4 + 1] = q.y;
        v[1 + i * 4 + 2] = q.z; v[1 + i * 4 + 3] = q.w;
    }
    v[17] = (l0 + 16 >= LL) ? 0.f : xr[l0 + 16];

    float s = 0.f, ss = 0.f;
#pragma unroll
    for (int i = 0; i < 16; ++i) {
        float y = fmaf(w0, v[i], fmaf(w1, v[i + 1], fmaf(w2, v[i + 2], cb)));
        s += y;
        ss = fmaf(y, y, ss);
    }

#pragma unroll
    for (int d = 32; d > 0; d >>= 1) {
        s  += __shfl_down(s,  d, 64);
        ss += __shfl_down(ss, d, 64);
    }
    __shared__ float ls[4], lss[4];
    const int wid = t >> 6, lane = t & 63;
    if (lane == 0) { ls[wid] = s; lss[wid] = ss; }
    __syncthreads();
    if (t == 0) {
        float S  = ls[0] + ls[1] + ls[2] + ls[3];
        float SS = lss[0] + lss[1] + lss[2] + lss[3];
        ws[c * 8 + b]        = S;
        ws[4096 + c * 8 + b] = SS;
    }
}

// ---------------- K2: finalize BN -> per-channel scale/shift ----------------
__global__ __launch_bounds__(512) void bn_finalize_kernel(
    const float* __restrict__ bn_gamma, const float* __restrict__ bn_beta,
    float* __restrict__ ws)
{
    const int c = threadIdx.x;  // 512 threads
    float s = 0.f, ss = 0.f;
#pragma unroll
    for (int b = 0; b < 8; ++b) {
        s  += ws[c * 8 + b];
        ss += ws[4096 + c * 8 + b];
    }
    const float inv  = 1.f / (float)(BB * LL);
    const float mean = s * inv;
    const float var  = ss * inv - mean * mean;
    const float sc   = bn_gamma[c] * rsqrtf(var + EPSV);
    ws[8192 + c] = sc;
    ws[8704 + c] = bn_beta[c] - mean * sc;
}

// ---------------- K3: fused feat + proj + softmax + deformable gather ----------------
__global__ __launch_bounds__(256) void fused_kernel(
    const float* __restrict__ x,
    const float* __restrict__ conv_w, const float* __restrict__ conv_b,
    const float* __restrict__ off_w,  const float* __restrict__ off_b,
    const float* __restrict__ wgt_w,  const float* __restrict__ wgt_b,
    const float* __restrict__ ws, float* __restrict__ out)
{
    __shared__ float xs[CC][XS_STRIDE];   // 22528 B : x[b, c, l0-1 .. l0+TL]
    __shared__ float ft[TL][FT_STRIDE];   // 16512 B : feat, l-major
    __shared__ float pr[TL][24];          //   768 B : [0,12) offsets, [12,24) weights

    const int t  = threadIdx.x;
    const int b  = blockIdx.y;
    const int l0 = blockIdx.x * TL;
    const float* xb = x + (size_t)b * CC * LL;
    const float* wsScale = ws + 8192;
    const float* wsShift = ws + 8704;

    // Phase A+B: load x rows (t, t+256), stage into xs, compute feat into ft.
#pragma unroll
    for (int r = 0; r < 2; ++r) {
        const int c = t + (r << 8);
        const float* xr = xb + (size_t)c * LL;
        float v[TL + 2];
        v[0] = (l0 == 0) ? 0.f : xr[l0 - 1];
#pragma unroll
        for (int i = 0; i < TL / 4; ++i) {
            float4 q = *reinterpret_cast<const float4*>(xr + l0 + i * 4);
            v[1 + i * 4 + 0] = q.x; v[1 + i * 4 + 1] = q.y;
            v[1 + i * 4 + 2] = q.z; v[1 + i * 4 + 3] = q.w;
        }
        v[TL + 1] = (l0 + TL >= LL) ? 0.f : xr[l0 + TL];

#pragma unroll
        for (int i = 0; i < TL + 2; ++i) xs[c][i] = v[i];

        const float w0 = conv_w[c * 3 + 0];
        const float w1 = conv_w[c * 3 + 1];
        const float w2 = conv_w[c * 3 + 2];
        const float sc = wsScale[c];
        const float sh = fmaf(conv_b[c], sc, wsShift[c]);
#pragma unroll
        for (int l = 0; l < TL; ++l) {
            float conv = fmaf(w0, v[l], fmaf(w1, v[l + 1], w2 * v[l + 2]));
            float z = fmaf(sc, conv, sh);
            ft[l][c] = 0.5f * z * (1.f + erff(z * 0.70710678118654752f));
        }
    }
    __syncthreads();

    // Phase C: 24 outputs x TL positions = 192 serial dots over C=512.
    if (t < 24 * TL) {
        const int o = t >> 3;       // /TL
        const int l = t & (TL - 1);
        const float* W = (o < 12) ? (off_w + o * CC) : (wgt_w + (o - 12) * CC);
        float ax = 0.f, ay = 0.f, az = 0.f, aw = 0.f;
#pragma unroll 4
        for (int i = 0; i < CC / 4; ++i) {
            float4 f = *reinterpret_cast<const float4*>(&ft[l][i * 4]);
            float4 w = *reinterpret_cast<const float4*>(W + i * 4);
            ax = fmaf(f.x, w.x, ax); ay = fmaf(f.y, w.y, ay);
            az = fmaf(f.z, w.z, az); aw = fmaf(f.w, w.w, aw);
        }
        float dv = (ax + ay) + (az + aw);
        dv += (o < 12) ? off_b[o] : wgt_b[o - 12];
        pr[l][o] = dv;
    }
    __syncthreads();

    // softmax over K=3 per (l, g)
    if (t < TL * GG) {
        const int l = t >> 2, g = t & 3;
        float a = pr[l][12 + g * 3 + 0];
        float b2 = pr[l][12 + g * 3 + 1];
        float c2 = pr[l][12 + g * 3 + 2];
        float m = fmaxf(a, fmaxf(b2, c2));
        float ea = __expf(a - m), eb = __expf(b2 - m), ec = __expf(c2 - m);
        float inv = 1.f / (ea + eb + ec);
        pr[l][12 + g * 3 + 0] = ea * inv;
        pr[l][12 + g * 3 + 1] = eb * inv;
        pr[l][12 + g * 3 + 2] = ec * inv;
    }
    __syncthreads();

    // Phase D: deformable gather + blend, write out[b, c, l0..l0+TL)
    float* ob = out + (size_t)b * CC * LL;
#pragma unroll
    for (int r = 0; r < 2; ++r) {
        const int c = t + (r << 8);
        const int g = c >> 7;           // group
        const float j = (float)(c & 127);
        const int gbase = g << 7;
        float oacc[TL];
#pragma unroll
        for (int l = 0; l < TL; ++l) oacc[l] = 0.f;

#pragma unroll
        for (int l = 0; l < TL; ++l) {
#pragma unroll
            for (int k = 0; k < KK; ++k) {
                const float off = pr[l][g * 3 + k];
                const float w   = pr[l][12 + g * 3 + k];
                float idx = fminf(fmaxf(j + off, 0.f), 127.f);
                float fl  = floorf(idx);
                float fr  = idx - fl;
                int i0 = (int)fl;
                int i1 = i0 + 1; if (i1 > 127) i1 = 127;
                float xf = xs[gbase + i0][l + 1];
                float xc = xs[gbase + i1][l + 1];
                oacc[l] = fmaf(w, fmaf(fr, xc - xf, xf), oacc[l]);
            }
        }
        float* orow = ob + (size_t)c * LL + l0;
#pragma unroll
        for (int i = 0; i < TL / 4; ++i) {
            float4 q = make_float4(oacc[i * 4 + 0], oacc[i * 4 + 1],
                                   oacc[i * 4 + 2], oacc[i * 4 + 3]);
            *reinterpret_cast<float4*>(orow + i * 4) = q;
        }
    }
}

extern "C" void kernel_launch(void* const* d_in, const int* in_sizes, int n_in,
                              void* d_out, int out_size, void* d_ws, size_t ws_size,
                              hipStream_t stream) {
    const float* x      = (const float*)d_in[1];
    const float* conv_w = (const float*)d_in[2];
    const float* conv_b = (const float*)d_in[3];
    const float* bn_g   = (const float*)d_in[4];
    const float* bn_b   = (const float*)d_in[5];
    const float* off_w  = (const float*)d_in[6];
    const float* off_b  = (const float*)d_in[7];
    const float* wgt_w  = (const float*)d_in[8];
    const float* wgt_b  = (const float*)d_in[9];
    float* out = (float*)d_out;
    float* ws  = (float*)d_ws;

    conv_stats_kernel<<<dim3(CC, BB), 256, 0, stream>>>(x, conv_w, conv_b, ws);
    bn_finalize_kernel<<<1, 512, 0, stream>>>(bn_g, bn_b, ws);
    fused_kernel<<<dim3(LL / TL, BB), 256, 0, stream>>>(
        x, conv_w, conv_b, off_w, off_b, wgt_w, wgt_b, ws, out);
}

// Round 3
// 235.224 us; speedup vs baseline: 1.1488x; 1.1488x over previous
//
#include <hip/hip_runtime.h>
#include <math.h>

#define BB 8
#define CC 512
#define LL 4096
#define GG 4
#define KK 3
#define EPSV 1e-5f

#define TL 8            // l-positions per tile in fused kernel
#define XSP (CC + 4)    // xs row stride (floats): lanes read consecutive c -> conflict-free
#define FTP (CC + 24)   // ftb row stride (ushorts): 536*2=1072B = 67*16 (16B-aligned rows)

// ws layout (floats):
//  [0,      4096) : psum[c*8+b]
//  [4096,   8192) : psq [c*8+b]
//  [8192,   8704) : scale[c]
//  [8704,   9216) : shift[c]   (= beta - mean*scale)

__device__ __forceinline__ float gelu_tanh(float z) {
    // 0.5*z*(1+tanh(0.79788456*(z+0.044715 z^3))) == z * sigmoid(1.59576912*(z+0.044715 z^3))
    float z2 = z * z;
    float a  = 1.5957691216f * fmaf(0.044715f * z2, z, z);
    return z * __builtin_amdgcn_rcpf(1.f + __expf(-a));
}

__device__ __forceinline__ ushort f32_to_bf16(float f) {
    uint u = __float_as_uint(f);
    return (ushort)((u + 0x7fffu + ((u >> 16) & 1u)) >> 16);   // RNE
}

// ---------------- K1: conv + per-(c,b) partial stats (lane-contiguous float4) ----------------
__global__ __launch_bounds__(256) void conv_stats_kernel(
    const float* __restrict__ x, const float* __restrict__ conv_w,
    const float* __restrict__ conv_b, float* __restrict__ ws)
{
    const int c = blockIdx.x;
    const int b = blockIdx.y;
    const int t = threadIdx.x;

    const float w0 = conv_w[c * 3 + 0];
    const float w1 = conv_w[c * 3 + 1];
    const float w2 = conv_w[c * 3 + 2];
    const float cb = conv_b[c];
    const float* xr = x + ((size_t)b * CC + c) * LL;

    float s = 0.f, ss = 0.f;
#pragma unroll
    for (int i = 0; i < 4; ++i) {
        const int l0 = 4 * (t + 256 * i);          // lanes contiguous -> coalesced
        float4 q = *reinterpret_cast<const float4*>(xr + l0);
        float lf = (l0 == 0) ? 0.f : xr[l0 - 1];   // L1 hit (same lines)
        float rt = (l0 + 4 >= LL) ? 0.f : xr[l0 + 4];
        float y;
        y = fmaf(w0, lf,  fmaf(w1, q.x, fmaf(w2, q.y, cb))); s += y; ss = fmaf(y, y, ss);
        y = fmaf(w0, q.x, fmaf(w1, q.y, fmaf(w2, q.z, cb))); s += y; ss = fmaf(y, y, ss);
        y = fmaf(w0, q.y, fmaf(w1, q.z, fmaf(w2, q.w, cb))); s += y; ss = fmaf(y, y, ss);
        y = fmaf(w0, q.z, fmaf(w1, q.w, fmaf(w2, rt,  cb))); s += y; ss = fmaf(y, y, ss);
    }

#pragma unroll
    for (int d = 32; d > 0; d >>= 1) {
        s  += __shfl_down(s,  d, 64);
        ss += __shfl_down(ss, d, 64);
    }
    __shared__ float ls[4], lss[4];
    const int wid = t >> 6, lane = t & 63;
    if (lane == 0) { ls[wid] = s; lss[wid] = ss; }
    __syncthreads();
    if (t == 0) {
        ws[c * 8 + b]        = ls[0] + ls[1] + ls[2] + ls[3];
        ws[4096 + c * 8 + b] = lss[0] + lss[1] + lss[2] + lss[3];
    }
}

// ---------------- K2: finalize BN -> per-channel scale/shift ----------------
__global__ __launch_bounds__(512) void bn_finalize_kernel(
    const float* __restrict__ bn_gamma, const float* __restrict__ bn_beta,
    float* __restrict__ ws)
{
    const int c = threadIdx.x;  // 512 threads
    float s = 0.f, ss = 0.f;
#pragma unroll
    for (int b = 0; b < 8; ++b) {
        s  += ws[c * 8 + b];
        ss += ws[4096 + c * 8 + b];
    }
    const float inv  = 1.f / (float)(BB * LL);
    const float mean = s * inv;
    const float var  = ss * inv - mean * mean;
    const float sc   = bn_gamma[c] * rsqrtf(var + EPSV);
    ws[8192 + c] = sc;
    ws[8704 + c] = bn_beta[c] - mean * sc;
}

// ---------------- K3: fused feat + proj + softmax + deformable gather ----------------
__global__ __launch_bounds__(256) void fused_kernel(
    const float* __restrict__ x,
    const float* __restrict__ conv_w, const float* __restrict__ conv_b,
    const float* __restrict__ off_w,  const float* __restrict__ off_b,
    const float* __restrict__ wgt_w,  const float* __restrict__ wgt_b,
    const float* __restrict__ ws, float* __restrict__ out)
{
    __shared__ float  xs[TL + 2][XSP];   // 20640 B : x[b, :, l0-1..l0+TL], l-major (transposed)
    __shared__ ushort ftb[TL][FTP];      //  8576 B : feat as bf16, l-major
    __shared__ float  pr[TL][24];        //   768 B : [0,12) offsets, [12,24) softmax weights
    // total ~30 KB -> 5 blocks/CU

    const int t = threadIdx.x;
    const int b = blockIdx.y;
    // XCD-chunked swizzle: XCD = blockIdx.x % 8 (512 tiles, 512%8==0, grid-linear id keeps bx%8);
    // XCD k handles contiguous l-tiles [64k, 64k+64) -> boundary cache lines shared in one L2.
    const int ltile = ((blockIdx.x & 7) << 6) + (blockIdx.x >> 3);
    const int l0 = ltile * TL;

    const float* xb = x + (size_t)b * CC * LL;
    const float* wsScale = ws + 8192;
    const float* wsShift = ws + 8704;

    // Phase A+B: load x rows (c = t, t+256), stage transposed into xs, feat(bf16) into ftb.
#pragma unroll
    for (int r = 0; r < 2; ++r) {
        const int c = t + (r << 8);
        const float* xr = xb + (size_t)c * LL;
        float v[TL + 2];
        v[0] = (l0 == 0) ? 0.f : xr[l0 - 1];
#pragma unroll
        for (int i = 0; i < TL / 4; ++i) {
            float4 q = *reinterpret_cast<const float4*>(xr + l0 + i * 4);
            v[1 + i * 4 + 0] = q.x; v[1 + i * 4 + 1] = q.y;
            v[1 + i * 4 + 2] = q.z; v[1 + i * 4 + 3] = q.w;
        }
        v[TL + 1] = (l0 + TL >= LL) ? 0.f : xr[l0 + TL];

#pragma unroll
        for (int i = 0; i < TL + 2; ++i) xs[i][c] = v[i];

        const float w0 = conv_w[c * 3 + 0];
        const float w1 = conv_w[c * 3 + 1];
        const float w2 = conv_w[c * 3 + 2];
        const float sc = wsScale[c];
        const float sh = fmaf(conv_b[c], sc, wsShift[c]);
#pragma unroll
        for (int l = 0; l < TL; ++l) {
            float conv = fmaf(w0, v[l], fmaf(w1, v[l + 1], w2 * v[l + 2]));
            float z = fmaf(sc, conv, sh);
            ftb[l][c] = f32_to_bf16(gelu_tanh(z));
        }
    }
    __syncthreads();

    // Phase C: 24 outputs x TL positions = 192 dots over C=512, feat read as bf16x8 per issue.
    if (t < 24 * TL) {
        const int o = t >> 3;       // 0..23 (same-o lanes share W addresses -> coalesced/broadcast)
        const int l = t & (TL - 1); // same-l lanes share ftb addresses -> LDS broadcast
        const float* W = (o < 12) ? (off_w + o * CC) : (wgt_w + (o - 12) * CC);
        const uint4* fp = reinterpret_cast<const uint4*>(&ftb[l][0]);
        float a0 = 0.f, a1 = 0.f, a2 = 0.f, a3 = 0.f;
#pragma unroll 4
        for (int i = 0; i < CC / 8; ++i) {
            uint4 u = fp[i];
            float4 wa = *reinterpret_cast<const float4*>(W + 8 * i);
            float4 wb = *reinterpret_cast<const float4*>(W + 8 * i + 4);
            a0 = fmaf(__uint_as_float(u.x << 16),          wa.x, a0);
            a1 = fmaf(__uint_as_float(u.x & 0xffff0000u),  wa.y, a1);
            a2 = fmaf(__uint_as_float(u.y << 16),          wa.z, a2);
            a3 = fmaf(__uint_as_float(u.y & 0xffff0000u),  wa.w, a3);
            a0 = fmaf(__uint_as_float(u.z << 16),          wb.x, a0);
            a1 = fmaf(__uint_as_float(u.z & 0xffff0000u),  wb.y, a1);
            a2 = fmaf(__uint_as_float(u.w << 16),          wb.z, a2);
            a3 = fmaf(__uint_as_float(u.w & 0xffff0000u),  wb.w, a3);
        }
        float dv = (a0 + a1) + (a2 + a3);
        dv += (o < 12) ? off_b[o] : wgt_b[o - 12];
        pr[l][o] = dv;
    }
    __syncthreads();

    // softmax over K=3 per (l, g)
    if (t < TL * GG) {
        const int l = t >> 2, g = t & 3;
        float a  = pr[l][12 + g * 3 + 0];
        float b2 = pr[l][12 + g * 3 + 1];
        float c2 = pr[l][12 + g * 3 + 2];
        float m = fmaxf(a, fmaxf(b2, c2));
        float ea = __expf(a - m), eb = __expf(b2 - m), ec = __expf(c2 - m);
        float inv = __builtin_amdgcn_rcpf(ea + eb + ec);
        pr[l][12 + g * 3 + 0] = ea * inv;
        pr[l][12 + g * 3 + 1] = eb * inv;
        pr[l][12 + g * 3 + 2] = ec * inv;
    }
    __syncthreads();

    // Phase D: deformable gather + blend, write out[b, c, l0..l0+TL)
    float* ob = out + (size_t)b * CC * LL;
#pragma unroll
    for (int r = 0; r < 2; ++r) {
        const int c = t + (r << 8);
        const int g = c >> 7;
        const float j = (float)(c & 127);
        const int gbase = g << 7;
        float oacc[TL];
#pragma unroll
        for (int l = 0; l < TL; ++l) oacc[l] = 0.f;

#pragma unroll
        for (int l = 0; l < TL; ++l) {
            const float* xrow = &xs[l + 1][gbase];
#pragma unroll
            for (int k = 0; k < KK; ++k) {
                const float off = pr[l][g * 3 + k];       // wave-uniform -> LDS broadcast
                const float w   = pr[l][12 + g * 3 + k];
                float idx = fminf(fmaxf(j + off, 0.f), 127.f);
                float fl  = floorf(idx);
                float fr  = idx - fl;
                int i0 = (int)fl;
                int i1 = i0 + 1; if (i1 > 127) i1 = 127;
                float xf = xrow[i0];                      // adjacent pair -> ds_read2_b32
                float xc = xrow[i1];
                oacc[l] = fmaf(w, fmaf(fr, xc - xf, xf), oacc[l]);
            }
        }
        float* orow = ob + (size_t)c * LL + l0;
#pragma unroll
        for (int i = 0; i < TL / 4; ++i) {
            *reinterpret_cast<float4*>(orow + i * 4) =
                make_float4(oacc[i * 4 + 0], oacc[i * 4 + 1], oacc[i * 4 + 2], oacc[i * 4 + 3]);
        }
    }
}

extern "C" void kernel_launch(void* const* d_in, const int* in_sizes, int n_in,
                              void* d_out, int out_size, void* d_ws, size_t ws_size,
                              hipStream_t stream) {
    const float* x      = (const float*)d_in[1];
    const float* conv_w = (const float*)d_in[2];
    const float* conv_b = (const float*)d_in[3];
    const float* bn_g   = (const float*)d_in[4];
    const float* bn_b   = (const float*)d_in[5];
    const float* off_w  = (const float*)d_in[6];
    const float* off_b  = (const float*)d_in[7];
    const float* wgt_w  = (const float*)d_in[8];
    const float* wgt_b  = (const float*)d_in[9];
    float* out = (float*)d_out;
    float* ws  = (float*)d_ws;

    conv_stats_kernel<<<dim3(CC, BB), 256, 0, stream>>>(x, conv_w, conv_b, ws);
    bn_finalize_kernel<<<1, 512, 0, stream>>>(bn_g, bn_b, ws);
    fused_kernel<<<dim3(LL / TL, BB), 256, 0, stream>>>(
        x, conv_w, conv_b, off_w, off_b, wgt_w, wgt_b, ws, out);
}

// Round 4
// 233.287 us; speedup vs baseline: 1.1583x; 1.0083x over previous
//
#include <hip/hip_runtime.h>
#include <math.h>

#define BB 8
#define CC 512
#define LL 4096
#define GG 4
#define KK 3
#define EPSV 1e-5f

#define TL 16                  // l-positions per tile in fused kernel
#define NTILE (LL / TL)        // 256
#define XSL 18                 // xs row length (ushorts); word-stride 9 (odd) -> <=2-way banks
#define FTP 520                // ftb row stride (ushorts); 1040B = 65*16 (16B-aligned rows)
#define WB_F32OFF 9216         // Wb bf16 [32][512] lives at ws float offset 9216 (32KB)

// ws layout (floats):
//  [0,4096) psum[c*8+b] | [4096,8192) psq | [8192,8704) scale[c] | [8704,9216) shift[c]
//  [9216, 9216+8192) : Wb as ushort[32][512] (rows 0-11 off_w, 12-23 wgt_w, 24-31 zero)

typedef float  f32x4_t  __attribute__((ext_vector_type(4)));
typedef __bf16 bf16x8_t __attribute__((ext_vector_type(8)));

__device__ __forceinline__ float gelu_tanh(float z) {
    float z2 = z * z;
    float a  = 1.5957691216f * fmaf(0.044715f * z2, z, z);
    return z * __builtin_amdgcn_rcpf(1.f + __expf(-a));
}

__device__ __forceinline__ ushort f32_to_bf16(float f) {
    uint u = __float_as_uint(f);
    return (ushort)((u + 0x7fffu + ((u >> 16) & 1u)) >> 16);   // RNE
}

__device__ __forceinline__ f32x4_t mfma_bf16(uint4 a, uint4 b, f32x4_t c) {
    return __builtin_amdgcn_mfma_f32_16x16x32_bf16(
        __builtin_bit_cast(bf16x8_t, a), __builtin_bit_cast(bf16x8_t, b), c, 0, 0, 0);
}

// ---------------- K1: conv + per-(c,b) partial stats ----------------
__global__ __launch_bounds__(256) void conv_stats_kernel(
    const float* __restrict__ x, const float* __restrict__ conv_w,
    const float* __restrict__ conv_b, float* __restrict__ ws)
{
    const int c = blockIdx.x;
    const int b = blockIdx.y;
    const int t = threadIdx.x;

    const float w0 = conv_w[c * 3 + 0];
    const float w1 = conv_w[c * 3 + 1];
    const float w2 = conv_w[c * 3 + 2];
    const float cb = conv_b[c];
    const float* xr = x + ((size_t)b * CC + c) * LL;

    float s = 0.f, ss = 0.f;
#pragma unroll
    for (int i = 0; i < 4; ++i) {
        const int l0 = 4 * (t + 256 * i);          // lanes contiguous -> coalesced
        float4 q = *reinterpret_cast<const float4*>(xr + l0);
        float lf = __shfl_up(q.w, 1);              // x[l0-1] from neighbor lane
        if ((t & 63) == 0) lf = (l0 == 0) ? 0.f : xr[l0 - 1];
        float rt = __shfl_down(q.x, 1);            // x[l0+4]
        if ((t & 63) == 63) rt = (l0 + 4 >= LL) ? 0.f : xr[l0 + 4];
        float y;
        y = fmaf(w0, lf,  fmaf(w1, q.x, fmaf(w2, q.y, cb))); s += y; ss = fmaf(y, y, ss);
        y = fmaf(w0, q.x, fmaf(w1, q.y, fmaf(w2, q.z, cb))); s += y; ss = fmaf(y, y, ss);
        y = fmaf(w0, q.y, fmaf(w1, q.z, fmaf(w2, q.w, cb))); s += y; ss = fmaf(y, y, ss);
        y = fmaf(w0, q.z, fmaf(w1, q.w, fmaf(w2, rt,  cb))); s += y; ss = fmaf(y, y, ss);
    }

#pragma unroll
    for (int d = 32; d > 0; d >>= 1) {
        s  += __shfl_down(s,  d, 64);
        ss += __shfl_down(ss, d, 64);
    }
    __shared__ float ls[4], lss[4];
    const int wid = t >> 6, lane = t & 63;
    if (lane == 0) { ls[wid] = s; lss[wid] = ss; }
    __syncthreads();
    if (t == 0) {
        ws[c * 8 + b]        = ls[0] + ls[1] + ls[2] + ls[3];
        ws[4096 + c * 8 + b] = lss[0] + lss[1] + lss[2] + lss[3];
    }
}

// ---------------- K2: BN finalize + W -> bf16 pre-convert ----------------
__global__ __launch_bounds__(512) void bn_finalize_kernel(
    const float* __restrict__ bn_gamma, const float* __restrict__ bn_beta,
    const float* __restrict__ off_w, const float* __restrict__ wgt_w,
    float* __restrict__ ws)
{
    const int t = threadIdx.x;  // 512
    {   // per-channel scale/shift
        const int c = t;
        float s = 0.f, ss = 0.f;
#pragma unroll
        for (int b = 0; b < 8; ++b) {
            s  += ws[c * 8 + b];
            ss += ws[4096 + c * 8 + b];
        }
        const float inv  = 1.f / (float)(BB * LL);
        const float mean = s * inv;
        const float var  = ss * inv - mean * mean;
        const float sc   = bn_gamma[c] * rsqrtf(var + EPSV);
        ws[8192 + c] = sc;
        ws[8704 + c] = bn_beta[c] - mean * sc;
    }
    // Wb[32][512] bf16: thread t -> row o = t>>4, k chunk (t&15)*32
    ushort* wb = reinterpret_cast<ushort*>(ws + WB_F32OFF);
    const int o  = t >> 4;
    const int k0 = (t & 15) * 32;
    uint* dst = reinterpret_cast<uint*>(wb + o * CC + k0);
    if (o < 24) {
        const float* src = (o < 12) ? (off_w + o * CC + k0) : (wgt_w + (o - 12) * CC + k0);
#pragma unroll 4
        for (int j = 0; j < 16; ++j) {
            float2 v = *reinterpret_cast<const float2*>(src + 2 * j);
            dst[j] = (uint)f32_to_bf16(v.x) | ((uint)f32_to_bf16(v.y) << 16);
        }
    } else {
#pragma unroll 4
        for (int j = 0; j < 16; ++j) dst[j] = 0u;
    }
}

// ---------------- K3: fused feat + MFMA proj + softmax + deformable gather ----------------
__global__ __launch_bounds__(512, 8) void fused_kernel(
    const float* __restrict__ x,
    const float* __restrict__ conv_w, const float* __restrict__ conv_b,
    const float* __restrict__ off_b,  const float* __restrict__ wgt_b,
    const float* __restrict__ ws, float* __restrict__ out)
{
    __shared__ ushort xsb[CC][XSL];      // 18432 B : x bf16, [c][l+1], l in [-1,16]
    __shared__ ushort ftb[TL][FTP];      // 16640 B : feat bf16, [l][c] (k-contiguous for MFMA A)
    __shared__ float  pr[TL][24];        //  1536 B : raw offsets (0-11) + raw wgt logits (12-23)
    __shared__ int    pdI[TL][GG][KK];   //   768 B : floor(offset)
    __shared__ float  pdA[TL][GG][KK];   //   768 B : w*(1-frac)
    __shared__ float  pdB[TL][GG][KK];   //   768 B : w*frac
    // total ~38.9 KB -> 4 blocks/CU; 512 thr -> 32 waves/CU

    const int t  = threadIdx.x;
    const int b  = blockIdx.y;
    const int bx = blockIdx.x;
    // XCD-chunked swizzle (256 tiles = 8 XCDs x 32 contiguous tiles)
    const int ltile = ((bx & 7) << 5) | (bx >> 3);
    const int l0 = ltile * TL;

    // ---- Phase A: load x row c=t, stage x (bf16) + feat (bf16) ----
    {
        const int c = t;
        const float* xr = x + ((size_t)b * CC + c) * LL;
        float q[TL + 2];
        q[0] = (l0 == 0) ? 0.f : xr[l0 - 1];
#pragma unroll
        for (int i = 0; i < TL / 4; ++i) {
            float4 v = *reinterpret_cast<const float4*>(xr + l0 + 4 * i);
            q[1 + 4*i] = v.x; q[2 + 4*i] = v.y; q[3 + 4*i] = v.z; q[4 + 4*i] = v.w;
        }
        q[TL + 1] = (l0 + TL >= LL) ? 0.f : xr[l0 + TL];

        uint* xrow = reinterpret_cast<uint*>(&xsb[c][0]);
#pragma unroll
        for (int jj = 0; jj < (TL + 2) / 2; ++jj)
            xrow[jj] = (uint)f32_to_bf16(q[2*jj]) | ((uint)f32_to_bf16(q[2*jj+1]) << 16);

        const float w0 = conv_w[c*3+0], w1 = conv_w[c*3+1], w2 = conv_w[c*3+2];
        const float sc = ws[8192 + c];
        const float sh = fmaf(conv_b[c], sc, ws[8704 + c]);
#pragma unroll
        for (int l = 0; l < TL; ++l) {
            float conv = fmaf(w0, q[l], fmaf(w1, q[l+1], w2 * q[l+2]));
            float z = fmaf(sc, conv, sh);
            ftb[l][c] = f32_to_bf16(gelu_tanh(z));
        }
    }
    __syncthreads();

    // ---- Phase C: projection via MFMA. D[m][o] = sum_k feat[m][k]*W[o][k].
    // A and B frags loaded with the SAME contiguous lane->k map, so the
    // contraction is correct for any HW k-permutation (operand symmetry).
    const int wv = t >> 6, lane = t & 63;
    if (wv < 2) {
        const int n  = lane & 15;             // A row (=l_pos) and B col (=output) index
        const int kb = (lane >> 4) * 8;       // k sub-offset
        const ushort* wrow = reinterpret_cast<const ushort*>(ws + WB_F32OFF) + (wv * 16 + n) * CC + kb;
        const ushort* arow = &ftb[n][kb];
        f32x4_t acc = {0.f, 0.f, 0.f, 0.f};
#pragma unroll
        for (int s = 0; s < CC / 32; ++s) {
            uint4 av = *reinterpret_cast<const uint4*>(arow + 32 * s);   // ds_read_b128
            uint4 bv = *reinterpret_cast<const uint4*>(wrow + 32 * s);   // global 16B (L1-hot)
            acc = mfma_bf16(av, bv, acc);
        }
        const int o = wv * 16 + n;
        if (o < 24) {
            float bias = (o < 12) ? off_b[o] : wgt_b[o - 12];
            const int rb = (lane >> 4) * 4;   // C/D: col=lane&15, row=(lane>>4)*4+i  [m89]
#pragma unroll
            for (int i = 0; i < 4; ++i) pr[rb + i][o] = acc[i] + bias;
        }
    }
    __syncthreads();

    // ---- softmax + gather-coefficient precompute: one thread per (l,g) ----
    if (t < TL * GG) {
        const int l = t >> 2, g = t & 3;
        float s0 = pr[l][12 + g*3 + 0];
        float s1 = pr[l][12 + g*3 + 1];
        float s2 = pr[l][12 + g*3 + 2];
        float m  = fmaxf(s0, fmaxf(s1, s2));
        float e0 = __expf(s0 - m), e1 = __expf(s1 - m), e2 = __expf(s2 - m);
        float inv = __builtin_amdgcn_rcpf(e0 + e1 + e2);
        float wk0 = e0 * inv, wk1 = e1 * inv, wk2 = e2 * inv;
        float wks[3] = {wk0, wk1, wk2};
#pragma unroll
        for (int k = 0; k < KK; ++k) {
            float off = pr[l][g*3 + k];
            float fo  = floorf(off);
            float fr  = off - fo;
            pdI[l][g][k] = (int)fo;
            pdA[l][g][k] = wks[k] * (1.f - fr);
            pdB[l][g][k] = wks[k] * fr;
        }
    }
    __syncthreads();

    // ---- Phase D: gather + blend, write out[b, c, l0..l0+16) ----
    {
        const int c  = t;
        const int g  = c >> 7;
        const int j  = c & 127;
        const int gb = g << 7;
        float* orow = out + ((size_t)b * CC + c) * LL + l0;
#pragma unroll
        for (int h = 0; h < 2; ++h) {
            float acc[8];
#pragma unroll
            for (int l = 0; l < 8; ++l) acc[l] = 0.f;
#pragma unroll
            for (int l = 0; l < 8; ++l) {
                const int ll = h * 8 + l;
#pragma unroll
                for (int k = 0; k < KK; ++k) {
                    const int   fo = pdI[ll][g][k];   // wave-uniform (64 | 128)
                    const float wa = pdA[ll][g][k];
                    const float wc = pdB[ll][g][k];
                    int p  = j + fo;
                    int i0 = min(max(p, 0), 127);
                    int i1 = min(max(p + 1, 0), 127);
                    float xf = __uint_as_float((uint)xsb[gb + i0][ll + 1] << 16);
                    float xc = __uint_as_float((uint)xsb[gb + i1][ll + 1] << 16);
                    acc[l] = fmaf(wa, xf, fmaf(wc, xc, acc[l]));
                }
            }
#pragma unroll
            for (int i = 0; i < 2; ++i) {
                *reinterpret_cast<float4*>(orow + h * 8 + 4 * i) =
                    make_float4(acc[4*i], acc[4*i+1], acc[4*i+2], acc[4*i+3]);
            }
        }
    }
}

extern "C" void kernel_launch(void* const* d_in, const int* in_sizes, int n_in,
                              void* d_out, int out_size, void* d_ws, size_t ws_size,
                              hipStream_t stream) {
    const float* x      = (const float*)d_in[1];
    const float* conv_w = (const float*)d_in[2];
    const float* conv_b = (const float*)d_in[3];
    const float* bn_g   = (const float*)d_in[4];
    const float* bn_b   = (const float*)d_in[5];
    const float* off_w  = (const float*)d_in[6];
    const float* off_b  = (const float*)d_in[7];
    const float* wgt_w  = (const float*)d_in[8];
    const float* wgt_b  = (const float*)d_in[9];
    float* out = (float*)d_out;
    float* ws  = (float*)d_ws;

    conv_stats_kernel<<<dim3(CC, BB), 256, 0, stream>>>(x, conv_w, conv_b, ws);
    bn_finalize_kernel<<<1, 512, 0, stream>>>(bn_g, bn_b, off_w, wgt_w, ws);
    fused_kernel<<<dim3(NTILE, BB), 512, 0, stream>>>(
        x, conv_w, conv_b, off_b, wgt_b, ws, out);
}